// Round 1
// baseline (3675.021 us; speedup 1.0000x reference)
//
#include <hip/hip_runtime.h>
#include <math.h>

#define NFIELD 3
#define FEAT 256   // D == O == 256

// ---------------- degree / normalization ----------------

__global__ void k_init_deg(float* deg, int n) {
    int i = blockIdx.x * blockDim.x + threadIdx.x;
    if (i < n) deg[i] = 2.0f;   // improved=True self-loop weight
}

__global__ void k_accum_deg(const int* __restrict__ col, const float* __restrict__ w,
                            float* deg, int E) {
    int e = blockIdx.x * blockDim.x + threadIdx.x;
    if (e < E) atomicAdd(&deg[col[e]], w[e]);
}

__global__ void k_rsqrt_inplace(float* deg, int n) {
    int i = blockIdx.x * blockDim.x + threadIdx.x;
    if (i < n) {
        float d = deg[i];
        deg[i] = d > 0.0f ? rsqrtf(d) : 0.0f;
    }
}

// ---------------- xa init (self-loop term) ----------------
// xa[fl, i, :] = 2*dinv[i]^2 * x[f_base+fl, i, :]
__global__ void k_init_xa(const float* __restrict__ x, const float* __restrict__ dinv,
                          float* __restrict__ xa, int n, int f_base, int fl_count) {
    int gid  = blockIdx.x * (blockDim.x / 64) + (threadIdx.x >> 6);
    int lane = threadIdx.x & 63;
    if (gid >= fl_count * n) return;
    int fl = gid / n;
    int r  = gid - fl * n;
    int f  = f_base + fl;
    float di = dinv[r];
    float s  = 2.0f * di * di;
    size_t sb = ((size_t)f  * n + r) * FEAT + lane * 4;
    size_t db = ((size_t)fl * n + r) * FEAT + lane * 4;
    float4 v = *(const float4*)(x + sb);
    float4 o;
    o.x = s * v.x; o.y = s * v.y; o.z = s * v.z; o.w = s * v.w;
    *(float4*)(xa + db) = o;
}

// ---------------- edge scatter ----------------
// one wave per (edge, field): xa[fl, col, :] += norm_e * x[f, row, :]
__global__ void k_scatter(const int* __restrict__ ei, const float* __restrict__ w,
                          const float* __restrict__ dinv, const float* __restrict__ x,
                          float* __restrict__ xa, int n, int E, int f_base, int fl_count) {
    int wid  = blockIdx.x * (blockDim.x / 64) + (threadIdx.x >> 6);
    int lane = threadIdx.x & 63;
    if (wid >= fl_count * E) return;
    int fl = wid / E;
    int e  = wid - fl * E;
    int f  = f_base + fl;
    int r  = ei[e];
    int c  = ei[E + e];
    float nrm = dinv[r] * w[e] * dinv[c];
    size_t sb = ((size_t)f  * n + r) * FEAT + lane * 4;
    size_t db = ((size_t)fl * n + c) * FEAT + lane * 4;
    float4 v = *(const float4*)(x + sb);
    atomicAdd(xa + db + 0, nrm * v.x);
    atomicAdd(xa + db + 1, nrm * v.y);
    atomicAdd(xa + db + 2, nrm * v.z);
    atomicAdd(xa + db + 3, nrm * v.w);
}

// ---------------- fused GEMM + highway + leaky_relu ----------------
// out[f,n,o] = leaky( g*(xa.Wg) + (1-g)*(x.Wr^T) ), g = sigmoid(x.Wh)
#define BM 64
#define BN 64
#define BK 16

__global__ __launch_bounds__(256) void k_gemm_fused(
    const float* __restrict__ x, const float* __restrict__ xa,
    const float* __restrict__ Wg, const float* __restrict__ Wr, const float* __restrict__ Wh,
    float* __restrict__ out, int n, int f_base) {

    __shared__ float As_x[BM][BK];
    __shared__ float As_a[BM][BK];
    __shared__ float Bs_g[BK][BN];
    __shared__ float Bs_r[BK][BN];
    __shared__ float Bs_h[BK][BN];

    int fl = blockIdx.z;
    int f  = f_base + fl;
    int m0 = blockIdx.x * BM;
    int o0 = blockIdx.y * BN;
    int t  = threadIdx.x;
    int tx = t & 15;       // 0..15 -> output col group
    int ty = t >> 4;       // 0..15 -> output row group

    const float* xf  = x  + (size_t)f  * n * FEAT;
    const float* xaf = xa + (size_t)fl * n * FEAT;
    const float* Wgf = Wg + (size_t)f * FEAT * FEAT;
    const float* Wrf = Wr + (size_t)f * FEAT * FEAT;
    const float* Whf = Wh + (size_t)f * FEAT * FEAT;

    float accg[4][4] = {{0}}, accr[4][4] = {{0}}, acch[4][4] = {{0}};

    // load-index precompute
    int lr   = t >> 2;          // 0..63  A-row within tile
    int lk4  = (t & 3) * 4;     // A k offset (float4)
    int bk   = t >> 4;          // 0..15  B k-row
    int bc4  = (t & 15) * 4;    // B col offset (float4)
    int rc   = t & 63;          // Wr: o col within tile
    int rk4  = (t >> 6) * 4;    // Wr: k offset (float4 along d)

    for (int k0 = 0; k0 < FEAT; k0 += BK) {
        int gr = m0 + lr;
        float4 vx = make_float4(0.f, 0.f, 0.f, 0.f);
        float4 va = make_float4(0.f, 0.f, 0.f, 0.f);
        if (gr < n) {
            vx = *(const float4*)(xf  + (size_t)gr * FEAT + k0 + lk4);
            va = *(const float4*)(xaf + (size_t)gr * FEAT + k0 + lk4);
        }
        *(float4*)&As_x[lr][lk4] = vx;
        *(float4*)&As_a[lr][lk4] = va;

        *(float4*)&Bs_g[bk][bc4] = *(const float4*)(Wgf + (size_t)(k0 + bk) * FEAT + o0 + bc4);
        *(float4*)&Bs_h[bk][bc4] = *(const float4*)(Whf + (size_t)(k0 + bk) * FEAT + o0 + bc4);

        float4 vr = *(const float4*)(Wrf + (size_t)(o0 + rc) * FEAT + k0 + rk4);
        Bs_r[rk4 + 0][rc] = vr.x;
        Bs_r[rk4 + 1][rc] = vr.y;
        Bs_r[rk4 + 2][rc] = vr.z;
        Bs_r[rk4 + 3][rc] = vr.w;

        __syncthreads();

        #pragma unroll
        for (int kk = 0; kk < BK; ++kk) {
            float ax[4], aa[4], bg[4], br[4], bh[4];
            #pragma unroll
            for (int i = 0; i < 4; ++i) {
                ax[i] = As_x[4 * ty + i][kk];
                aa[i] = As_a[4 * ty + i][kk];
            }
            #pragma unroll
            for (int j = 0; j < 4; ++j) {
                bg[j] = Bs_g[kk][4 * tx + j];
                br[j] = Bs_r[kk][4 * tx + j];
                bh[j] = Bs_h[kk][4 * tx + j];
            }
            #pragma unroll
            for (int i = 0; i < 4; ++i)
                #pragma unroll
                for (int j = 0; j < 4; ++j) {
                    accg[i][j] += aa[i] * bg[j];
                    accr[i][j] += ax[i] * br[j];
                    acch[i][j] += ax[i] * bh[j];
                }
        }
        __syncthreads();
    }

    // epilogue: highway gate + leaky relu
    #pragma unroll
    for (int i = 0; i < 4; ++i) {
        int gr = m0 + 4 * ty + i;
        if (gr >= n) continue;
        float4 ov;
        float* o = (float*)&ov;
        #pragma unroll
        for (int j = 0; j < 4; ++j) {
            float g = 1.0f / (1.0f + __expf(-acch[i][j]));
            float v = g * accg[i][j] + (1.0f - g) * accr[i][j];
            o[j] = v >= 0.0f ? v : 0.01f * v;
        }
        *(float4*)(out + ((size_t)f * n + gr) * FEAT + o0 + 4 * tx) = ov;
    }
}

// ---------------- launcher ----------------

extern "C" void kernel_launch(void* const* d_in, const int* in_sizes, int n_in,
                              void* d_out, int out_size, void* d_ws, size_t ws_size,
                              hipStream_t stream) {
    const float* x  = (const float*)d_in[0];
    const int*   ei = (const int*)d_in[1];
    const float* ew = (const float*)d_in[2];
    const float* Wg = (const float*)d_in[3];
    const float* Wr = (const float*)d_in[4];
    const float* Wh = (const float*)d_in[5];
    float* out = (float*)d_out;

    const int n = in_sizes[0] / (NFIELD * FEAT);   // 20000
    const int E = in_sizes[2];                     // 320000

    float* deg = (float*)d_ws;                                   // n floats (becomes dinv)
    float* xa  = (float*)((char*)d_ws + (size_t)(1 << 20));      // fl_count * n * FEAT floats

    const size_t per_field = (size_t)n * FEAT * sizeof(float);
    const size_t need_full = (size_t)(1 << 20) + NFIELD * per_field;
    const int full = (ws_size >= need_full) ? 1 : 0;

    // 1) degree + rsqrt (shared across fields)
    k_init_deg<<<(n + 255) / 256, 256, 0, stream>>>(deg, n);
    k_accum_deg<<<(E + 255) / 256, 256, 0, stream>>>(ei + E, ew, deg, E);
    k_rsqrt_inplace<<<(n + 255) / 256, 256, 0, stream>>>(deg, n);

    if (full) {
        const int fl = NFIELD;
        int rows = fl * n;
        k_init_xa<<<(rows + 3) / 4, 256, 0, stream>>>(x, deg, xa, n, 0, fl);
        int waves = fl * E;
        k_scatter<<<(waves + 3) / 4, 256, 0, stream>>>(ei, ew, deg, x, xa, n, E, 0, fl);
        dim3 g((n + BM - 1) / BM, FEAT / BN, fl);
        k_gemm_fused<<<g, 256, 0, stream>>>(x, xa, Wg, Wr, Wh, out, n, 0);
    } else {
        for (int f = 0; f < NFIELD; ++f) {
            int rows = n;
            k_init_xa<<<(rows + 3) / 4, 256, 0, stream>>>(x, deg, xa, n, f, 1);
            int waves = E;
            k_scatter<<<(waves + 3) / 4, 256, 0, stream>>>(ei, ew, deg, x, xa, n, E, f, 1);
            dim3 g((n + BM - 1) / BM, FEAT / BN, 1);
            k_gemm_fused<<<g, 256, 0, stream>>>(x, xa, Wg, Wr, Wh, out, n, f);
        }
    }
}

// Round 2
// 691.428 us; speedup vs baseline: 5.3151x; 5.3151x over previous
//
#include <hip/hip_runtime.h>
#include <math.h>

#define NFIELD 3
#define FEAT 256   // D == O == 256

// ---------------- CSR build: count / scan / fill ----------------

__global__ void k_zero(float* dnrm, int* count, int n) {
    int i = blockIdx.x * blockDim.x + threadIdx.x;
    if (i < n) { dnrm[i] = 2.0f; count[i] = 0; }   // self-loop weight 2.0
}

__global__ void k_count(const int* __restrict__ col, const float* __restrict__ w,
                        float* dnrm, int* count, int E) {
    int e = blockIdx.x * blockDim.x + threadIdx.x;
    if (e < E) {
        int c = col[e];
        atomicAdd(&count[c], 1);
        atomicAdd(&dnrm[c], w[e]);
    }
}

#define SCAN_T 1024
__global__ __launch_bounds__(SCAN_T) void k_scan(const int* __restrict__ count,
        float* dnrm, int* rowptr, int* cursor, int n, int E) {
    __shared__ int part[SCAN_T];
    int t = threadIdx.x;
    int ch = (n + SCAN_T - 1) / SCAN_T;
    int c0 = t * ch, c1 = min(n, c0 + ch);
    int s = 0;
    for (int c = c0; c < c1; ++c) s += count[c];
    part[t] = s;
    __syncthreads();
    for (int off = 1; off < SCAN_T; off <<= 1) {
        int v = (t >= off) ? part[t - off] : 0;
        __syncthreads();
        part[t] += v;
        __syncthreads();
    }
    int base = part[t] - s;   // exclusive prefix
    for (int c = c0; c < c1; ++c) {
        rowptr[c] = base; cursor[c] = base; base += count[c];
        float d = dnrm[c];
        dnrm[c] = d > 0.0f ? rsqrtf(d) : 0.0f;   // deg >= 2 always, but keep guard
    }
    if (t == 0) rowptr[n] = E;
}

__global__ void k_fill(const int* __restrict__ col, int* cursor, int* eidx, int E) {
    int e = blockIdx.x * blockDim.x + threadIdx.x;
    if (e < E) {
        int p = atomicAdd(&cursor[col[e]], 1);
        eidx[p] = e;
    }
}

// ---------------- gather: xa[fl,c,:] = 2*dinv^2*x[f,c,:] + sum_e nrm*x[f,row_e,:] ----------------
// one wave per destination node; all fl_count fields per wave (amortizes index loads)
__global__ void k_gather(const int* __restrict__ ei, const float* __restrict__ ew,
                         const float* __restrict__ dnrm, const int* __restrict__ rowptr,
                         const int* __restrict__ eidx, const float* __restrict__ x,
                         float* __restrict__ xa, int n, int E, int f_base, int fl_count) {
    int wid  = blockIdx.x * (blockDim.x >> 6) + (threadIdx.x >> 6);
    int lane = threadIdx.x & 63;
    if (wid >= n) return;
    int c = wid;
    int beg = rowptr[c], end = rowptr[c + 1];
    float dc = dnrm[c];
    float s  = 2.0f * dc * dc;

    float4 acc[NFIELD];
    #pragma unroll
    for (int fl = 0; fl < NFIELD; ++fl) {
        if (fl >= fl_count) break;
        float4 v = *((const float4*)(x + ((size_t)(f_base + fl) * n + c) * FEAT) + lane);
        acc[fl].x = s * v.x; acc[fl].y = s * v.y; acc[fl].z = s * v.z; acc[fl].w = s * v.w;
    }
    for (int i = beg; i < end; ++i) {
        int e = eidx[i];
        int r = ei[e];
        float nm = dnrm[r] * ew[e] * dc;
        #pragma unroll
        for (int fl = 0; fl < NFIELD; ++fl) {
            if (fl >= fl_count) break;
            float4 v = *((const float4*)(x + ((size_t)(f_base + fl) * n + r) * FEAT) + lane);
            acc[fl].x += nm * v.x; acc[fl].y += nm * v.y;
            acc[fl].z += nm * v.z; acc[fl].w += nm * v.w;
        }
    }
    #pragma unroll
    for (int fl = 0; fl < NFIELD; ++fl) {
        if (fl >= fl_count) break;
        *((float4*)(xa + ((size_t)fl * n + c) * FEAT) + lane) = acc[fl];
    }
}

// ---------------- fused GEMM + highway + leaky_relu ----------------
// out[f,n,o] = leaky( g*(xa.Wg) + (1-g)*(x.Wr^T) ), g = sigmoid(x.Wh)
#define BM 64
#define BN 64
#define BK 16

__global__ __launch_bounds__(256) void k_gemm_fused(
    const float* __restrict__ x, const float* __restrict__ xa,
    const float* __restrict__ Wg, const float* __restrict__ Wr, const float* __restrict__ Wh,
    float* __restrict__ out, int n, int f_base) {

    __shared__ float As_x[BM][BK];
    __shared__ float As_a[BM][BK];
    __shared__ float Bs_g[BK][BN];
    __shared__ float Bs_r[BK][BN];
    __shared__ float Bs_h[BK][BN];

    int fl = blockIdx.z;
    int f  = f_base + fl;
    int m0 = blockIdx.x * BM;
    int o0 = blockIdx.y * BN;
    int t  = threadIdx.x;
    int tx = t & 15;
    int ty = t >> 4;

    const float* xf  = x  + (size_t)f  * n * FEAT;
    const float* xaf = xa + (size_t)fl * n * FEAT;
    const float* Wgf = Wg + (size_t)f * FEAT * FEAT;
    const float* Wrf = Wr + (size_t)f * FEAT * FEAT;
    const float* Whf = Wh + (size_t)f * FEAT * FEAT;

    float accg[4][4] = {{0}}, accr[4][4] = {{0}}, acch[4][4] = {{0}};

    int lr   = t >> 2;
    int lk4  = (t & 3) * 4;
    int bk   = t >> 4;
    int bc4  = (t & 15) * 4;
    int rc   = t & 63;
    int rk4  = (t >> 6) * 4;

    for (int k0 = 0; k0 < FEAT; k0 += BK) {
        int gr = m0 + lr;
        float4 vx = make_float4(0.f, 0.f, 0.f, 0.f);
        float4 va = make_float4(0.f, 0.f, 0.f, 0.f);
        if (gr < n) {
            vx = *(const float4*)(xf  + (size_t)gr * FEAT + k0 + lk4);
            va = *(const float4*)(xaf + (size_t)gr * FEAT + k0 + lk4);
        }
        *(float4*)&As_x[lr][lk4] = vx;
        *(float4*)&As_a[lr][lk4] = va;

        *(float4*)&Bs_g[bk][bc4] = *(const float4*)(Wgf + (size_t)(k0 + bk) * FEAT + o0 + bc4);
        *(float4*)&Bs_h[bk][bc4] = *(const float4*)(Whf + (size_t)(k0 + bk) * FEAT + o0 + bc4);

        float4 vr = *(const float4*)(Wrf + (size_t)(o0 + rc) * FEAT + k0 + rk4);
        Bs_r[rk4 + 0][rc] = vr.x;
        Bs_r[rk4 + 1][rc] = vr.y;
        Bs_r[rk4 + 2][rc] = vr.z;
        Bs_r[rk4 + 3][rc] = vr.w;

        __syncthreads();

        #pragma unroll
        for (int kk = 0; kk < BK; ++kk) {
            float ax[4], aa[4], bg[4], br[4], bh[4];
            #pragma unroll
            for (int i = 0; i < 4; ++i) {
                ax[i] = As_x[4 * ty + i][kk];
                aa[i] = As_a[4 * ty + i][kk];
            }
            #pragma unroll
            for (int j = 0; j < 4; ++j) {
                bg[j] = Bs_g[kk][4 * tx + j];
                br[j] = Bs_r[kk][4 * tx + j];
                bh[j] = Bs_h[kk][4 * tx + j];
            }
            #pragma unroll
            for (int i = 0; i < 4; ++i)
                #pragma unroll
                for (int j = 0; j < 4; ++j) {
                    accg[i][j] += aa[i] * bg[j];
                    accr[i][j] += ax[i] * br[j];
                    acch[i][j] += ax[i] * bh[j];
                }
        }
        __syncthreads();
    }

    #pragma unroll
    for (int i = 0; i < 4; ++i) {
        int gr = m0 + 4 * ty + i;
        if (gr >= n) continue;
        float4 ov;
        float* o = (float*)&ov;
        #pragma unroll
        for (int j = 0; j < 4; ++j) {
            float g = 1.0f / (1.0f + __expf(-acch[i][j]));
            float v = g * accg[i][j] + (1.0f - g) * accr[i][j];
            o[j] = v >= 0.0f ? v : 0.01f * v;
        }
        *(float4*)(out + ((size_t)f * n + gr) * FEAT + o0 + 4 * tx) = ov;
    }
}

// ---------------- launcher ----------------

static inline size_t align_up(size_t v, size_t a) { return (v + a - 1) & ~(a - 1); }

extern "C" void kernel_launch(void* const* d_in, const int* in_sizes, int n_in,
                              void* d_out, int out_size, void* d_ws, size_t ws_size,
                              hipStream_t stream) {
    const float* x  = (const float*)d_in[0];
    const int*   ei = (const int*)d_in[1];
    const float* ew = (const float*)d_in[2];
    const float* Wg = (const float*)d_in[3];
    const float* Wr = (const float*)d_in[4];
    const float* Wh = (const float*)d_in[5];
    float* out = (float*)d_out;

    const int n = in_sizes[0] / (NFIELD * FEAT);   // 20000
    const int E = in_sizes[2];                     // 320000

    // tight workspace layout
    char* base = (char*)d_ws;
    size_t off = 0;
    float* dnrm   = (float*)(base + off); off = align_up(off + (size_t)n * 4, 256);
    int*   count  = (int*)  (base + off); off = align_up(off + (size_t)n * 4, 256);
    int*   rowptr = (int*)  (base + off); off = align_up(off + (size_t)(n + 1) * 4, 256);
    int*   cursor = (int*)  (base + off); off = align_up(off + (size_t)n * 4, 256);
    int*   eidx   = (int*)  (base + off); off = align_up(off + (size_t)E * 4, 1024);
    float* xa     = (float*)(base + off);
    const size_t per_field = (size_t)n * FEAT * sizeof(float);
    const int full = (ws_size >= off + NFIELD * per_field) ? 1 : 0;

    const int* row = ei;
    const int* col = ei + E;

    // CSR build (shared across fields)
    k_zero <<<(n + 255) / 256, 256, 0, stream>>>(dnrm, count, n);
    k_count<<<(E + 255) / 256, 256, 0, stream>>>(col, ew, dnrm, count, E);
    k_scan <<<1, SCAN_T, 0, stream>>>(count, dnrm, rowptr, cursor, n, E);
    k_fill <<<(E + 255) / 256, 256, 0, stream>>>(col, cursor, eidx, E);

    if (full) {
        int blocks = (n + 3) / 4;   // 4 waves per 256-thread block
        k_gather<<<blocks, 256, 0, stream>>>(ei, ew, dnrm, rowptr, eidx, x, xa, n, E, 0, NFIELD);
        dim3 g((n + BM - 1) / BM, FEAT / BN, NFIELD);
        k_gemm_fused<<<g, 256, 0, stream>>>(x, xa, Wg, Wr, Wh, out, n, 0);
    } else {
        for (int f = 0; f < NFIELD; ++f) {
            int blocks = (n + 3) / 4;
            k_gather<<<blocks, 256, 0, stream>>>(ei, ew, dnrm, rowptr, eidx, x, xa, n, E, f, 1);
            dim3 g((n + BM - 1) / BM, FEAT / BN, 1);
            k_gemm_fused<<<g, 256, 0, stream>>>(x, xa, Wg, Wr, Wh, out, n, f);
        }
    }
}

// Round 4
// 393.722 us; speedup vs baseline: 9.3340x; 1.7561x over previous
//
#include <hip/hip_runtime.h>
#include <math.h>

#define NFIELD 3
#define FEAT 256   // D == O == 256

typedef __attribute__((ext_vector_type(8))) short frag_ab;   // 8 bf16 (4 VGPRs)
typedef __attribute__((ext_vector_type(4))) float frag_cd;   // 4 fp32 acc

__device__ __forceinline__ unsigned short f2bf(float f) {
    unsigned int u = __float_as_uint(f);
    u = (u + 0x7fffu + ((u >> 16) & 1u)) >> 16;   // RNE
    return (unsigned short)u;
}
__device__ __forceinline__ float bf2f(unsigned short b) {
    return __uint_as_float(((unsigned int)b) << 16);
}

// ---------------- CSR build: count / scan / fill ----------------

__global__ void k_zero(float* dnrm, int* count, int n) {
    int i = blockIdx.x * blockDim.x + threadIdx.x;
    if (i < n) { dnrm[i] = 2.0f; count[i] = 0; }   // improved self-loop weight 2.0
}

__global__ void k_count(const int* __restrict__ col, const float* __restrict__ w,
                        float* dnrm, int* count, int E) {
    int e = blockIdx.x * blockDim.x + threadIdx.x;
    if (e < E) {
        int c = col[e];
        atomicAdd(&count[c], 1);
        atomicAdd(&dnrm[c], w[e]);
    }
}

#define SCAN_T 1024
__global__ __launch_bounds__(SCAN_T) void k_scan(const int* __restrict__ count,
        float* dnrm, int* rowptr, int* cursor, int n, int E) {
    __shared__ int part[SCAN_T];
    int t = threadIdx.x;
    int ch = (n + SCAN_T - 1) / SCAN_T;
    int c0 = t * ch, c1 = min(n, c0 + ch);
    int s = 0;
    for (int c = c0; c < c1; ++c) s += count[c];
    part[t] = s;
    __syncthreads();
    for (int off = 1; off < SCAN_T; off <<= 1) {
        int v = (t >= off) ? part[t - off] : 0;
        __syncthreads();
        part[t] += v;
        __syncthreads();
    }
    int base = part[t] - s;   // exclusive prefix
    for (int c = c0; c < c1; ++c) {
        rowptr[c] = base; cursor[c] = base; base += count[c];
        float d = dnrm[c];
        dnrm[c] = d > 0.0f ? rsqrtf(d) : 0.0f;
    }
    if (t == 0) rowptr[n] = E;
}

__global__ void k_fill(const int* __restrict__ col, int* cursor, int* eidx, int E) {
    int e = blockIdx.x * blockDim.x + threadIdx.x;
    if (e < E) {
        int p = atomicAdd(&cursor[col[e]], 1);
        eidx[p] = e;
    }
}

// ---------------- conversions ----------------

// x fp32 -> bf16, contiguous range (fields are outermost dim)
__global__ void k_cvt_x(const float* __restrict__ src, unsigned short* __restrict__ dst,
                        int count4) {
    int i = blockIdx.x * blockDim.x + threadIdx.x;
    if (i >= count4) return;
    float4 v = *((const float4*)src + i);
    ushort4 o;
    o.x = f2bf(v.x); o.y = f2bf(v.y); o.z = f2bf(v.z); o.w = f2bf(v.w);
    *((ushort4*)dst + i) = o;
}

// weights -> bf16, all in [f][o][k] layout (Wg/Wh transposed, Wr straight)
__global__ void k_cvt_w(const float* __restrict__ Wg, const float* __restrict__ Wr,
                        const float* __restrict__ Wh,
                        unsigned short* __restrict__ wgT, unsigned short* __restrict__ wrT,
                        unsigned short* __restrict__ whT) {
    int i = blockIdx.x * blockDim.x + threadIdx.x;          // over NFIELD*256*256
    if (i >= NFIELD * FEAT * FEAT) return;
    int f = i >> 16;
    int r = i & 0xffff;
    int d = r >> 8;          // k index in source row-major [d][o]
    int o = r & 255;
    int tdst = (f << 16) | (o << 8) | d;
    wgT[tdst] = f2bf(Wg[i]);
    whT[tdst] = f2bf(Wh[i]);
    wrT[i]    = f2bf(Wr[i]);   // already [o][k]
}

// ---------------- gather (bf16 in, bf16 out, fp32 accumulate) ----------------
// xa[fl,c,:] = 2*dinv_c^2 * x[fl,c,:] + sum_e dinv_r*w_e*dinv_c * x[fl,row_e,:]
__global__ void k_gather(const int* __restrict__ ei, const float* __restrict__ ew,
                         const float* __restrict__ dnrm, const int* __restrict__ rowptr,
                         const int* __restrict__ eidx,
                         const unsigned short* __restrict__ xb,
                         unsigned short* __restrict__ xab,
                         int n, int E, int fl_count) {
    int wid  = blockIdx.x * (blockDim.x >> 6) + (threadIdx.x >> 6);
    int lane = threadIdx.x & 63;
    if (wid >= n) return;
    int c = wid;
    int beg = rowptr[c], end = rowptr[c + 1];
    float dc = dnrm[c];
    float s  = 2.0f * dc * dc;

    float acc[NFIELD][4];
    #pragma unroll
    for (int fl = 0; fl < NFIELD; ++fl) {
        if (fl >= fl_count) break;
        ushort4 v = *((const ushort4*)(xb + ((size_t)fl * n + c) * FEAT) + lane);
        acc[fl][0] = s * bf2f(v.x); acc[fl][1] = s * bf2f(v.y);
        acc[fl][2] = s * bf2f(v.z); acc[fl][3] = s * bf2f(v.w);
    }
    for (int i = beg; i < end; ++i) {
        int e = eidx[i];
        int r = ei[e];
        float nm = dnrm[r] * ew[e] * dc;
        #pragma unroll
        for (int fl = 0; fl < NFIELD; ++fl) {
            if (fl >= fl_count) break;
            ushort4 v = *((const ushort4*)(xb + ((size_t)fl * n + r) * FEAT) + lane);
            acc[fl][0] += nm * bf2f(v.x); acc[fl][1] += nm * bf2f(v.y);
            acc[fl][2] += nm * bf2f(v.z); acc[fl][3] += nm * bf2f(v.w);
        }
    }
    #pragma unroll
    for (int fl = 0; fl < NFIELD; ++fl) {
        if (fl >= fl_count) break;
        ushort4 o;
        o.x = f2bf(acc[fl][0]); o.y = f2bf(acc[fl][1]);
        o.z = f2bf(acc[fl][2]); o.w = f2bf(acc[fl][3]);
        *((ushort4*)(xab + ((size_t)fl * n + c) * FEAT) + lane) = o;
    }
}

// ---------------- MFMA GEMM + highway + leaky_relu ----------------
// out[f,m,o] = leaky( g*(xa.WgT^T) + (1-g)*(x.WrT^T) ), g = sigmoid(x.WhT^T)
// all weight buffers are [o][k]; LDS tiles are [row][k] with XOR quad swizzle.
#define BM 64
#define BN 64
#define BK 32

__device__ __forceinline__ int swz(int row, int quad) {
    return (quad ^ ((row >> 1) & 3)) * 8;
}

__global__ __launch_bounds__(256) void k_gemm_mfma(
    const unsigned short* __restrict__ xb, const unsigned short* __restrict__ xab,
    const unsigned short* __restrict__ wgT, const unsigned short* __restrict__ wrT,
    const unsigned short* __restrict__ whT,
    float* __restrict__ out, int n, int f_base) {

    __shared__ unsigned short As_x[BM][BK];
    __shared__ unsigned short As_a[BM][BK];
    __shared__ unsigned short Bs_g[BN][BK];
    __shared__ unsigned short Bs_r[BN][BK];
    __shared__ unsigned short Bs_h[BN][BK];

    int fl = blockIdx.z;
    int f  = f_base + fl;
    int m0 = blockIdx.x * BM;
    int o0 = blockIdx.y * BN;
    int t  = threadIdx.x;

    const unsigned short* xf  = xb  + (size_t)fl * n * FEAT;
    const unsigned short* xaf = xab + (size_t)fl * n * FEAT;
    const unsigned short* wg  = wgT + ((size_t)f << 16);
    const unsigned short* wr  = wrT + ((size_t)f << 16);
    const unsigned short* wh  = whT + ((size_t)f << 16);

    // staging indices: thread t loads 16B (8 bf16) of row (t>>2), quad (t&3)
    int srow = t >> 2;
    int sq   = t & 3;
    int sdst = swz(srow, sq);                    // element offset within the 32-wide row
    int skel = sq * 8;                           // logical k offset

    // wave / lane for MFMA
    int w      = t >> 6;
    int lane   = t & 63;
    int lrow   = lane & 15;
    int quad   = lane >> 4;
    int m_half = (w >> 1) * 32;
    int n_half = (w & 1) * 32;

    frag_cd accg[2][2], accr[2][2], acch[2][2];
    #pragma unroll
    for (int mi = 0; mi < 2; ++mi)
        #pragma unroll
        for (int ni = 0; ni < 2; ++ni) {
            accg[mi][ni] = (frag_cd){0.f, 0.f, 0.f, 0.f};
            accr[mi][ni] = (frag_cd){0.f, 0.f, 0.f, 0.f};
            acch[mi][ni] = (frag_cd){0.f, 0.f, 0.f, 0.f};
        }

    int am = min(m0 + srow, n - 1);              // clamp A row (stores are guarded)
    const uint4* pax = (const uint4*)(xf  + (size_t)am * FEAT + skel);
    const uint4* paa = (const uint4*)(xaf + (size_t)am * FEAT + skel);
    const uint4* pbg = (const uint4*)(wg + ((o0 + srow) << 8) + skel);
    const uint4* pbr = (const uint4*)(wr + ((o0 + srow) << 8) + skel);
    const uint4* pbh = (const uint4*)(wh + ((o0 + srow) << 8) + skel);
    const int kstep = BK / 8;                    // uint4s per BK advance (BUG FIX: was ++)

    for (int k0 = 0; k0 < FEAT; k0 += BK) {
        *(uint4*)&As_x[srow][sdst] = *pax; pax += kstep;
        *(uint4*)&As_a[srow][sdst] = *paa; paa += kstep;
        *(uint4*)&Bs_g[srow][sdst] = *pbg; pbg += kstep;
        *(uint4*)&Bs_r[srow][sdst] = *pbr; pbr += kstep;
        *(uint4*)&Bs_h[srow][sdst] = *pbh; pbh += kstep;
        __syncthreads();

        frag_ab ax[2], aa[2], bg[2], br[2], bh[2];
        #pragma unroll
        for (int mi = 0; mi < 2; ++mi) {
            int r = m_half + mi * 16 + lrow;
            int c = swz(r, quad);
            ax[mi] = *(const frag_ab*)&As_x[r][c];
            aa[mi] = *(const frag_ab*)&As_a[r][c];
        }
        #pragma unroll
        for (int ni = 0; ni < 2; ++ni) {
            int r = n_half + ni * 16 + lrow;
            int c = swz(r, quad);
            bg[ni] = *(const frag_ab*)&Bs_g[r][c];
            br[ni] = *(const frag_ab*)&Bs_r[r][c];
            bh[ni] = *(const frag_ab*)&Bs_h[r][c];
        }
        #pragma unroll
        for (int mi = 0; mi < 2; ++mi)
            #pragma unroll
            for (int ni = 0; ni < 2; ++ni) {
                accg[mi][ni] = __builtin_amdgcn_mfma_f32_16x16x32_bf16(aa[mi], bg[ni], accg[mi][ni], 0, 0, 0);
                accr[mi][ni] = __builtin_amdgcn_mfma_f32_16x16x32_bf16(ax[mi], br[ni], accr[mi][ni], 0, 0, 0);
                acch[mi][ni] = __builtin_amdgcn_mfma_f32_16x16x32_bf16(ax[mi], bh[ni], acch[mi][ni], 0, 0, 0);
            }
        __syncthreads();
    }

    // epilogue: C/D layout col=lane&15, row=quad*4+i  (m89/m91-verified)
    #pragma unroll
    for (int mi = 0; mi < 2; ++mi)
        #pragma unroll
        for (int ni = 0; ni < 2; ++ni)
            #pragma unroll
            for (int i = 0; i < 4; ++i) {
                int grow = m0 + m_half + mi * 16 + quad * 4 + i;
                if (grow >= n) continue;
                float h = acch[mi][ni][i];
                float g = 1.0f / (1.0f + __expf(-h));
                float v = g * accg[mi][ni][i] + (1.0f - g) * accr[mi][ni][i];
                v = v >= 0.0f ? v : 0.01f * v;
                out[((size_t)f * n + grow) * FEAT + o0 + n_half + ni * 16 + lrow] = v;
            }
}

// ---------------- launcher ----------------

static inline size_t align_up(size_t v, size_t a) { return (v + a - 1) & ~(a - 1); }

extern "C" void kernel_launch(void* const* d_in, const int* in_sizes, int n_in,
                              void* d_out, int out_size, void* d_ws, size_t ws_size,
                              hipStream_t stream) {
    const float* x  = (const float*)d_in[0];
    const int*   ei = (const int*)d_in[1];
    const float* ew = (const float*)d_in[2];
    const float* Wg = (const float*)d_in[3];
    const float* Wr = (const float*)d_in[4];
    const float* Wh = (const float*)d_in[5];
    float* out = (float*)d_out;

    const int n = in_sizes[0] / (NFIELD * FEAT);   // 20000
    const int E = in_sizes[2];                     // 320000

    char* base = (char*)d_ws;
    size_t off = 0;
    float* dnrm   = (float*)(base + off); off = align_up(off + (size_t)n * 4, 256);
    int*   count  = (int*)  (base + off); off = align_up(off + (size_t)n * 4, 256);
    int*   rowptr = (int*)  (base + off); off = align_up(off + (size_t)(n + 1) * 4, 256);
    int*   cursor = (int*)  (base + off); off = align_up(off + (size_t)n * 4, 256);
    int*   eidx   = (int*)  (base + off); off = align_up(off + (size_t)E * 4, 256);
    unsigned short* wgT = (unsigned short*)(base + off); off = align_up(off + (size_t)NFIELD * FEAT * FEAT * 2, 256);
    unsigned short* wrT = (unsigned short*)(base + off); off = align_up(off + (size_t)NFIELD * FEAT * FEAT * 2, 256);
    unsigned short* whT = (unsigned short*)(base + off); off = align_up(off + (size_t)NFIELD * FEAT * FEAT * 2, 256);
    size_t fixed = off;

    const size_t per_field = (size_t)n * FEAT * 2;   // bf16
    int fl;
    if (ws_size >= fixed + 2 * (size_t)NFIELD * per_field + 1024) fl = NFIELD;
    else fl = 1;
    unsigned short* xb  = (unsigned short*)(base + fixed);
    unsigned short* xab = (unsigned short*)(base + align_up(fixed + (size_t)fl * per_field, 256));

    const int* col = ei + E;

    // CSR build + normalization (shared across fields)
    k_zero <<<(n + 255) / 256, 256, 0, stream>>>(dnrm, count, n);
    k_count<<<(E + 255) / 256, 256, 0, stream>>>(col, ew, dnrm, count, E);
    k_scan <<<1, SCAN_T, 0, stream>>>(count, dnrm, rowptr, cursor, n, E);
    k_fill <<<(E + 255) / 256, 256, 0, stream>>>(col, cursor, eidx, E);

    // weights -> bf16 [o][k] (all fields, tiny)
    {
        int cnt = NFIELD * FEAT * FEAT;
        k_cvt_w<<<(cnt + 255) / 256, 256, 0, stream>>>(Wg, Wr, Wh, wgT, wrT, whT);
    }

    int gblocks = (n + 3) / 4;          // 4 waves per 256-thread block
    dim3 ggemm((n + BM - 1) / BM, FEAT / BN, fl);

    if (fl == NFIELD) {
        int cnt4 = NFIELD * n * FEAT / 4;
        k_cvt_x<<<(cnt4 + 255) / 256, 256, 0, stream>>>(x, xb, cnt4);
        k_gather<<<gblocks, 256, 0, stream>>>(ei, ew, dnrm, rowptr, eidx, xb, xab, n, E, NFIELD);
        k_gemm_mfma<<<ggemm, 256, 0, stream>>>(xb, xab, wgT, wrT, whT, out, n, 0);
    } else {
        for (int f = 0; f < NFIELD; ++f) {
            int cnt4 = n * FEAT / 4;
            k_cvt_x<<<(cnt4 + 255) / 256, 256, 0, stream>>>(x + (size_t)f * n * FEAT, xb, cnt4);
            k_gather<<<gblocks, 256, 0, stream>>>(ei, ew, dnrm, rowptr, eidx, xb, xab, n, E, 1);
            k_gemm_mfma<<<ggemm, 256, 0, stream>>>(xb, xab, wgT, wrT, whT, out, n, f);
        }
    }
}

// Round 5
// 356.102 us; speedup vs baseline: 10.3201x; 1.1056x over previous
//
#include <hip/hip_runtime.h>
#include <math.h>

#define NFIELD 3
#define FEAT 256   // D == O == 256

typedef __attribute__((ext_vector_type(8))) short frag_ab;   // 8 bf16 (4 VGPRs)
typedef __attribute__((ext_vector_type(4))) float frag_cd;   // 4 fp32 acc

__device__ __forceinline__ unsigned short f2bf(float f) {
    unsigned int u = __float_as_uint(f);
    u = (u + 0x7fffu + ((u >> 16) & 1u)) >> 16;   // RNE
    return (unsigned short)u;
}
__device__ __forceinline__ float bf2f(unsigned short b) {
    return __uint_as_float(((unsigned int)b) << 16);
}

// ---------------- CSR build: count / scan / fill ----------------

__global__ void k_zero(float* dnrm, int* count, int n) {
    int i = blockIdx.x * blockDim.x + threadIdx.x;
    if (i < n) { dnrm[i] = 2.0f; count[i] = 0; }   // improved self-loop weight 2.0
}

__global__ void k_count(const int* __restrict__ col, const float* __restrict__ w,
                        float* dnrm, int* count, int E) {
    int e = blockIdx.x * blockDim.x + threadIdx.x;
    if (e < E) {
        int c = col[e];
        atomicAdd(&count[c], 1);
        atomicAdd(&dnrm[c], w[e]);
    }
}

#define SCAN_T 1024
__global__ __launch_bounds__(SCAN_T) void k_scan(const int* __restrict__ count,
        float* dnrm, int* rowptr, int* cursor, int n, int E) {
    __shared__ int part[SCAN_T];
    int t = threadIdx.x;
    int ch = (n + SCAN_T - 1) / SCAN_T;
    int c0 = t * ch, c1 = min(n, c0 + ch);
    int s = 0;
    for (int c = c0; c < c1; ++c) s += count[c];
    part[t] = s;
    __syncthreads();
    for (int off = 1; off < SCAN_T; off <<= 1) {
        int v = (t >= off) ? part[t - off] : 0;
        __syncthreads();
        part[t] += v;
        __syncthreads();
    }
    int base = part[t] - s;   // exclusive prefix
    for (int c = c0; c < c1; ++c) {
        rowptr[c] = base; cursor[c] = base; base += count[c];
        float d = dnrm[c];
        dnrm[c] = d > 0.0f ? rsqrtf(d) : 0.0f;
    }
    if (t == 0) rowptr[n] = E;
}

// fill packed edge records: (src row, precomputed norm) — removes the
// eidx->ei/ew/dnrm pointer chase from the gather inner loop.
__global__ void k_fill(const int* __restrict__ ei, const float* __restrict__ ew,
                       const float* __restrict__ dnrm, int* cursor,
                       int2* __restrict__ erec, int E) {
    int e = blockIdx.x * blockDim.x + threadIdx.x;
    if (e < E) {
        int r = ei[e];
        int c = ei[E + e];
        float nm = dnrm[r] * ew[e] * dnrm[c];
        int p = atomicAdd(&cursor[c], 1);
        erec[p] = make_int2(r, __float_as_int(nm));
    }
}

// ---------------- conversions ----------------

__global__ void k_cvt_x(const float* __restrict__ src, unsigned short* __restrict__ dst,
                        int count4) {
    int i = blockIdx.x * blockDim.x + threadIdx.x;
    if (i >= count4) return;
    float4 v = *((const float4*)src + i);
    ushort4 o;
    o.x = f2bf(v.x); o.y = f2bf(v.y); o.z = f2bf(v.z); o.w = f2bf(v.w);
    *((ushort4*)dst + i) = o;
}

// weights -> bf16, all in [f][o][k] layout (Wg/Wh transposed, Wr straight)
__global__ void k_cvt_w(const float* __restrict__ Wg, const float* __restrict__ Wr,
                        const float* __restrict__ Wh,
                        unsigned short* __restrict__ wgT, unsigned short* __restrict__ wrT,
                        unsigned short* __restrict__ whT) {
    int i = blockIdx.x * blockDim.x + threadIdx.x;          // over NFIELD*256*256
    if (i >= NFIELD * FEAT * FEAT) return;
    int f = i >> 16;
    int r = i & 0xffff;
    int d = r >> 8;          // k index in source row-major [d][o]
    int o = r & 255;
    int tdst = (f << 16) | (o << 8) | d;
    wgT[tdst] = f2bf(Wg[i]);
    whT[tdst] = f2bf(Wh[i]);
    wrT[i]    = f2bf(Wr[i]);   // already [o][k]
}

// ---------------- gather (bf16 in, bf16 out, fp32 accumulate) ----------------
// xa[fl,c,:] = 2*dinv_c^2 * x[fl,c,:] + sum_e nrm_e * x[fl,src_e,:]
// one wave per destination node; 2-edge unroll -> 6 row loads in flight.
__global__ void k_gather(const int2* __restrict__ erec,
                         const float* __restrict__ dnrm, const int* __restrict__ rowptr,
                         const unsigned short* __restrict__ xb,
                         unsigned short* __restrict__ xab,
                         int n, int fl_count) {
    int wid  = blockIdx.x * (blockDim.x >> 6) + (threadIdx.x >> 6);
    int lane = threadIdx.x & 63;
    if (wid >= n) return;
    int c = wid;
    int beg = rowptr[c], end = rowptr[c + 1];
    float dc = dnrm[c];
    float s  = 2.0f * dc * dc;
    const size_t nf = (size_t)n * FEAT;

    float acc[NFIELD][4];
    #pragma unroll
    for (int fl = 0; fl < NFIELD; ++fl) {
        if (fl >= fl_count) break;
        ushort4 v = ((const ushort4*)(xb + fl * nf + (size_t)c * FEAT))[lane];
        acc[fl][0] = s * bf2f(v.x); acc[fl][1] = s * bf2f(v.y);
        acc[fl][2] = s * bf2f(v.z); acc[fl][3] = s * bf2f(v.w);
    }

    int i = beg;
    if (fl_count == NFIELD) {
        for (; i + 1 < end; i += 2) {
            int2 ra = erec[i];
            int2 rb = erec[i + 1];
            const unsigned short* pa = xb + (size_t)ra.x * FEAT;
            const unsigned short* pb = xb + (size_t)rb.x * FEAT;
            float na = __int_as_float(ra.y);
            float nb = __int_as_float(rb.y);
            ushort4 va0 = ((const ushort4*)pa)[lane];
            ushort4 vb0 = ((const ushort4*)pb)[lane];
            ushort4 va1 = ((const ushort4*)(pa + nf))[lane];
            ushort4 vb1 = ((const ushort4*)(pb + nf))[lane];
            ushort4 va2 = ((const ushort4*)(pa + 2 * nf))[lane];
            ushort4 vb2 = ((const ushort4*)(pb + 2 * nf))[lane];
            acc[0][0] += na * bf2f(va0.x) + nb * bf2f(vb0.x);
            acc[0][1] += na * bf2f(va0.y) + nb * bf2f(vb0.y);
            acc[0][2] += na * bf2f(va0.z) + nb * bf2f(vb0.z);
            acc[0][3] += na * bf2f(va0.w) + nb * bf2f(vb0.w);
            acc[1][0] += na * bf2f(va1.x) + nb * bf2f(vb1.x);
            acc[1][1] += na * bf2f(va1.y) + nb * bf2f(vb1.y);
            acc[1][2] += na * bf2f(va1.z) + nb * bf2f(vb1.z);
            acc[1][3] += na * bf2f(va1.w) + nb * bf2f(vb1.w);
            acc[2][0] += na * bf2f(va2.x) + nb * bf2f(vb2.x);
            acc[2][1] += na * bf2f(va2.y) + nb * bf2f(vb2.y);
            acc[2][2] += na * bf2f(va2.z) + nb * bf2f(vb2.z);
            acc[2][3] += na * bf2f(va2.w) + nb * bf2f(vb2.w);
        }
        for (; i < end; ++i) {
            int2 ra = erec[i];
            const unsigned short* pa = xb + (size_t)ra.x * FEAT;
            float na = __int_as_float(ra.y);
            ushort4 va0 = ((const ushort4*)pa)[lane];
            ushort4 va1 = ((const ushort4*)(pa + nf))[lane];
            ushort4 va2 = ((const ushort4*)(pa + 2 * nf))[lane];
            acc[0][0] += na * bf2f(va0.x); acc[0][1] += na * bf2f(va0.y);
            acc[0][2] += na * bf2f(va0.z); acc[0][3] += na * bf2f(va0.w);
            acc[1][0] += na * bf2f(va1.x); acc[1][1] += na * bf2f(va1.y);
            acc[1][2] += na * bf2f(va1.z); acc[1][3] += na * bf2f(va1.w);
            acc[2][0] += na * bf2f(va2.x); acc[2][1] += na * bf2f(va2.y);
            acc[2][2] += na * bf2f(va2.z); acc[2][3] += na * bf2f(va2.w);
        }
    } else {
        for (; i < end; ++i) {
            int2 ra = erec[i];
            const unsigned short* pa = xb + (size_t)ra.x * FEAT;
            float na = __int_as_float(ra.y);
            ushort4 va0 = ((const ushort4*)pa)[lane];
            acc[0][0] += na * bf2f(va0.x); acc[0][1] += na * bf2f(va0.y);
            acc[0][2] += na * bf2f(va0.z); acc[0][3] += na * bf2f(va0.w);
        }
    }

    #pragma unroll
    for (int fl = 0; fl < NFIELD; ++fl) {
        if (fl >= fl_count) break;
        ushort4 o;
        o.x = f2bf(acc[fl][0]); o.y = f2bf(acc[fl][1]);
        o.z = f2bf(acc[fl][2]); o.w = f2bf(acc[fl][3]);
        ((ushort4*)(xab + fl * nf + (size_t)c * FEAT))[lane] = o;
    }
}

// ---------------- MFMA GEMM + highway + leaky_relu ----------------
// out[f,m,o] = leaky( g*(xa.WgT^T) + (1-g)*(x.WrT^T) ), g = sigmoid(x.WhT^T)
// weights in [o][k]; LDS tiles [row][k] with XOR quad swizzle (0 conflicts, R4-verified).
// 64x128 block tile: A read 2x from memory (was 4x), 24 MFMA : 14 ds_read per wave-iter.
#define BM 64
#define BN 128
#define BK 32

__device__ __forceinline__ int swz(int row, int quad) {
    return (quad ^ ((row >> 1) & 3)) * 8;
}

__global__ __launch_bounds__(256) void k_gemm_mfma(
    const unsigned short* __restrict__ xb, const unsigned short* __restrict__ xab,
    const unsigned short* __restrict__ wgT, const unsigned short* __restrict__ wrT,
    const unsigned short* __restrict__ whT,
    float* __restrict__ out, int n, int f_base) {

    __shared__ unsigned short As_x[BM][BK];
    __shared__ unsigned short As_a[BM][BK];
    __shared__ unsigned short Bs[3][BN][BK];   // g, r, h

    int fl = blockIdx.z;
    int f  = f_base + fl;
    int m0 = blockIdx.x * BM;
    int o0 = blockIdx.y * BN;
    int t  = threadIdx.x;

    const unsigned short* xf  = xb  + (size_t)fl * n * FEAT;
    const unsigned short* xaf = xab + (size_t)fl * n * FEAT;
    const unsigned short* wsrc0 = wgT + ((size_t)f << 16);
    const unsigned short* wsrc1 = wrT + ((size_t)f << 16);
    const unsigned short* wsrc2 = whT + ((size_t)f << 16);

    int w    = t >> 6;
    int lane = t & 63;
    int lrow = lane & 15;
    int quad = lane >> 4;
    int wn   = w * 32;      // wave's 32-col window of the 128-wide tile

    frag_cd acc[3][4][2];   // stream (g,r,h), mi, ni
    #pragma unroll
    for (int s = 0; s < 3; ++s)
        #pragma unroll
        for (int mi = 0; mi < 4; ++mi)
            #pragma unroll
            for (int ni = 0; ni < 2; ++ni)
                acc[s][mi][ni] = (frag_cd){0.f, 0.f, 0.f, 0.f};

    // A staging: thread t -> row t>>2 (0..63), 16B chunk t&3
    int arow = t >> 2;
    int aq   = (t & 3) * 8;
    int adst = swz(arow, t & 3);
    int am   = min(m0 + arow, n - 1);           // clamp loads; stores guarded

    for (int k0 = 0; k0 < FEAT; k0 += BK) {
        *(uint4*)&As_x[arow][adst] = *(const uint4*)(xf  + (size_t)am * FEAT + k0 + aq);
        *(uint4*)&As_a[arow][adst] = *(const uint4*)(xaf + (size_t)am * FEAT + k0 + aq);
        #pragma unroll
        for (int s = 0; s < 6; ++s) {
            int buf = s >> 1;                          // uniform per unrolled s
            int row = (s & 1) * 64 + (t >> 2);         // 0..127
            const unsigned short* wsrc = (buf == 0) ? wsrc0 : (buf == 1) ? wsrc1 : wsrc2;
            *(uint4*)&Bs[buf][row][swz(row, t & 3)] =
                *(const uint4*)(wsrc + ((o0 + row) << 8) + k0 + aq);
        }
        __syncthreads();

        frag_ab ax[4], aa[4], bg[2], br[2], bh[2];
        #pragma unroll
        for (int mi = 0; mi < 4; ++mi) {
            int r = mi * 16 + lrow;
            int c = swz(r, quad);
            ax[mi] = *(const frag_ab*)&As_x[r][c];
            aa[mi] = *(const frag_ab*)&As_a[r][c];
        }
        #pragma unroll
        for (int ni = 0; ni < 2; ++ni) {
            int r = wn + ni * 16 + lrow;
            int c = swz(r, quad);
            bg[ni] = *(const frag_ab*)&Bs[0][r][c];
            br[ni] = *(const frag_ab*)&Bs[1][r][c];
            bh[ni] = *(const frag_ab*)&Bs[2][r][c];
        }
        #pragma unroll
        for (int mi = 0; mi < 4; ++mi)
            #pragma unroll
            for (int ni = 0; ni < 2; ++ni) {
                acc[0][mi][ni] = __builtin_amdgcn_mfma_f32_16x16x32_bf16(aa[mi], bg[ni], acc[0][mi][ni], 0, 0, 0);
                acc[1][mi][ni] = __builtin_amdgcn_mfma_f32_16x16x32_bf16(ax[mi], br[ni], acc[1][mi][ni], 0, 0, 0);
                acc[2][mi][ni] = __builtin_amdgcn_mfma_f32_16x16x32_bf16(ax[mi], bh[ni], acc[2][mi][ni], 0, 0, 0);
            }
        __syncthreads();
    }

    // epilogue: C/D layout col=lane&15, row=quad*4+i (m89/m91-verified)
    #pragma unroll
    for (int mi = 0; mi < 4; ++mi)
        #pragma unroll
        for (int ni = 0; ni < 2; ++ni)
            #pragma unroll
            for (int i = 0; i < 4; ++i) {
                int grow = m0 + mi * 16 + quad * 4 + i;
                if (grow >= n) continue;
                float h = acc[2][mi][ni][i];
                float g = 1.0f / (1.0f + __expf(-h));
                float v = g * acc[0][mi][ni][i] + (1.0f - g) * acc[1][mi][ni][i];
                v = v >= 0.0f ? v : 0.01f * v;
                out[((size_t)f * n + grow) * FEAT + o0 + wn + ni * 16 + lrow] = v;
            }
}

// ---------------- launcher ----------------

static inline size_t align_up(size_t v, size_t a) { return (v + a - 1) & ~(a - 1); }

extern "C" void kernel_launch(void* const* d_in, const int* in_sizes, int n_in,
                              void* d_out, int out_size, void* d_ws, size_t ws_size,
                              hipStream_t stream) {
    const float* x  = (const float*)d_in[0];
    const int*   ei = (const int*)d_in[1];
    const float* ew = (const float*)d_in[2];
    const float* Wg = (const float*)d_in[3];
    const float* Wr = (const float*)d_in[4];
    const float* Wh = (const float*)d_in[5];
    float* out = (float*)d_out;

    const int n = in_sizes[0] / (NFIELD * FEAT);   // 20000
    const int E = in_sizes[2];                     // 320000

    char* base = (char*)d_ws;
    size_t off = 0;
    float* dnrm   = (float*)(base + off); off = align_up(off + (size_t)n * 4, 256);
    int*   count  = (int*)  (base + off); off = align_up(off + (size_t)n * 4, 256);
    int*   rowptr = (int*)  (base + off); off = align_up(off + (size_t)(n + 1) * 4, 256);
    int*   cursor = (int*)  (base + off); off = align_up(off + (size_t)n * 4, 256);
    int2*  erec   = (int2*) (base + off); off = align_up(off + (size_t)E * 8, 256);
    unsigned short* wgT = (unsigned short*)(base + off); off = align_up(off + (size_t)NFIELD * FEAT * FEAT * 2, 256);
    unsigned short* wrT = (unsigned short*)(base + off); off = align_up(off + (size_t)NFIELD * FEAT * FEAT * 2, 256);
    unsigned short* whT = (unsigned short*)(base + off); off = align_up(off + (size_t)NFIELD * FEAT * FEAT * 2, 256);
    size_t fixed = off;

    const size_t per_field = (size_t)n * FEAT * 2;   // bf16
    int fl;
    if (ws_size >= fixed + 2 * (size_t)NFIELD * per_field + 1024) fl = NFIELD;
    else fl = 1;
    unsigned short* xb  = (unsigned short*)(base + fixed);
    unsigned short* xab = (unsigned short*)(base + align_up(fixed + (size_t)fl * per_field, 256));

    const int* col = ei + E;

    // CSR build + normalization (shared across fields)
    k_zero <<<(n + 255) / 256, 256, 0, stream>>>(dnrm, count, n);
    k_count<<<(E + 255) / 256, 256, 0, stream>>>(col, ew, dnrm, count, E);
    k_scan <<<1, SCAN_T, 0, stream>>>(count, dnrm, rowptr, cursor, n, E);
    k_fill <<<(E + 255) / 256, 256, 0, stream>>>(ei, ew, dnrm, cursor, erec, E);

    // weights -> bf16 [o][k]
    {
        int cnt = NFIELD * FEAT * FEAT;
        k_cvt_w<<<(cnt + 255) / 256, 256, 0, stream>>>(Wg, Wr, Wh, wgT, wrT, whT);
    }

    int gblocks = (n + 3) / 4;          // 4 waves per 256-thread block
    dim3 ggemm((n + BM - 1) / BM, FEAT / BN, fl);

    if (fl == NFIELD) {
        int cnt4 = NFIELD * n * FEAT / 4;
        k_cvt_x<<<(cnt4 + 255) / 256, 256, 0, stream>>>(x, xb, cnt4);
        k_gather<<<gblocks, 256, 0, stream>>>(erec, dnrm, rowptr, xb, xab, n, NFIELD);
        k_gemm_mfma<<<ggemm, 256, 0, stream>>>(xb, xab, wgT, wrT, whT, out, n, 0);
    } else {
        for (int f = 0; f < NFIELD; ++f) {
            int cnt4 = n * FEAT / 4;
            k_cvt_x<<<(cnt4 + 255) / 256, 256, 0, stream>>>(x + (size_t)f * n * FEAT, xb, cnt4);
            k_gather<<<gblocks, 256, 0, stream>>>(erec, dnrm, rowptr, xb, xab, n, 1);
            k_gemm_mfma<<<ggemm, 256, 0, stream>>>(xb, xab, wgT, wrT, whT, out, n, f);
        }
    }
}